// Round 2
// baseline (310.425 us; speedup 1.0000x reference)
//
#include <hip/hip_runtime.h>
#include <math.h>

#define BATCH 1024
#define SEQ   200
#define DIN   128
#define DOUT  128
#define HALF  64
#define PSTR  608    // partial-delta row stride (floats): 600 data + 8 pad

typedef __attribute__((ext_vector_type(8))) short short8;
typedef __attribute__((ext_vector_type(4))) float f32x4;

// fp32 -> packed (bf16_hi << 16) | bf16_lo ; hi = round-half-up, lo = RTZ residual
__device__ __forceinline__ unsigned pack_split(float f) {
    unsigned u = __float_as_uint(f);
    unsigned r = u + 0x8000u;
    unsigned hi = r >> 16;
    float hf = __uint_as_float(r & 0xffff0000u);
    unsigned lo = __float_as_uint(f - hf) >> 16;
    return (hi << 16) | lo;
}

__device__ __forceinline__ void split2(float f, short& h, short& l) {
    unsigned u = __float_as_uint(f);
    unsigned r = u + 0x8000u;
    h = (short)(r >> 16);
    float hf = __uint_as_float(r & 0xffff0000u);
    l = (short)(__float_as_uint(f - hf) >> 16);
}

// exact reconstruction of packed value
__device__ __forceinline__ float unpk(unsigned u) {
    return __uint_as_float(u & 0xffff0000u) + __uint_as_float(u << 16);
}

// ---- pre-split S into MFMA B-fragment order (hi at idx, lo at 16384+idx) ----
__global__ __launch_bounds__(256) void k_presplit(const float* __restrict__ S,
                                                  short* __restrict__ Sp) {
    int g = blockIdx.x * 256 + threadIdx.x;          // 0..16383
    int j = g & 7, lane = (g >> 3) & 63, kt = (g >> 9) & 3, nt = g >> 11;
    int k = kt * 32 + (lane >> 4) * 8 + j;
    int n = nt * 16 + (lane & 15);
    short h, l;
    split2(S[k * DOUT + n], h, l);
    Sp[g] = h;
    Sp[16384 + g] = l;
}

// ---- K1: low_new = A @ S ; LDS-free streaming version.
//      S fragments read straight from global (64 KB, permanently L2-resident;
//      each read is a coalesced 1KB/wave dwordx4, same address across blocks).
//      No __syncthreads, no LDS -> occupancy limited by VGPR only:
//      ~112 regs -> 4 waves/SIMD = 16 waves/CU (2x the LDS-staged version). ----
__global__ __launch_bounds__(256, 4) void k_gemm(const float* __restrict__ A,
                                                 const short* __restrict__ Sp,
                                                 unsigned* __restrict__ outp) {
    const int t = threadIdx.x;
    const int w = t >> 6, lane = t & 63;
    const int q = lane >> 4, c = lane & 15;
    const long rowb = (long)blockIdx.x * 128 + w * 32;

    // (1) all 16 A-loads issued first
    float4 araw[4][2][2];
#pragma unroll
    for (int kt = 0; kt < 4; ++kt)
#pragma unroll
        for (int mt = 0; mt < 2; ++mt) {
            const float* ap = A + (rowb + mt * 16 + c) * DIN + kt * 32 + q * 8;
            araw[kt][mt][0] = *(const float4*)ap;
            araw[kt][mt][1] = *(const float4*)(ap + 4);
        }

    // (2) split A into hi/lo bf16 fragments
    short8 ah[4][2], al[4][2];
#pragma unroll
    for (int kt = 0; kt < 4; ++kt)
#pragma unroll
        for (int mt = 0; mt < 2; ++mt) {
            float av[8];
            *(float4*)&av[0] = araw[kt][mt][0];
            *(float4*)&av[4] = araw[kt][mt][1];
#pragma unroll
            for (int j = 0; j < 8; ++j) {
                short h, l;
                split2(av[j], h, l);
                ah[kt][mt][j] = h; al[kt][mt][j] = l;
            }
        }

    f32x4 acc[2][8];
    const f32x4 zz = {0.f, 0.f, 0.f, 0.f};
#pragma unroll
    for (int mt = 0; mt < 2; ++mt)
#pragma unroll
        for (int nt = 0; nt < 8; ++nt) acc[mt][nt] = zz;

    // (3) MFMA loop: S fragments from global (L2-hit), pipelined by compiler
#pragma unroll
    for (int nt = 0; nt < 8; ++nt)
#pragma unroll
        for (int kt = 0; kt < 4; ++kt) {
            const short* sp = Sp + ((nt * 4 + kt) * 64 + lane) * 8;
            short8 sh = *(const short8*)sp;
            short8 sl = *(const short8*)(sp + 16384);
#pragma unroll
            for (int mt = 0; mt < 2; ++mt) {
                acc[mt][nt] = __builtin_amdgcn_mfma_f32_16x16x32_bf16(ah[kt][mt], sh, acc[mt][nt], 0, 0, 0);
                acc[mt][nt] = __builtin_amdgcn_mfma_f32_16x16x32_bf16(al[kt][mt], sh, acc[mt][nt], 0, 0, 0);
                acc[mt][nt] = __builtin_amdgcn_mfma_f32_16x16x32_bf16(ah[kt][mt], sl, acc[mt][nt], 0, 0, 0);
            }
        }

    // C/D: col = lane&15, row = (lane>>4)*4 + r
#pragma unroll
    for (int mt = 0; mt < 2; ++mt)
#pragma unroll
        for (int nt = 0; nt < 8; ++nt) {
            long r0 = rowb + mt * 16 + q * 4;
#pragma unroll
            for (int r = 0; r < 4; ++r)
                outp[(r0 + r) * DOUT + nt * 16 + c] = pack_split(acc[mt][nt][r]);
        }
}

// ---- K2: one routing iteration; NO LDS staging of low_new (LLC-resident),
//          LDS ~7 KB -> high occupancy. ----
__global__ __launch_bounds__(256, 6) void k_iter(
    const unsigned* __restrict__ lowp,   // [B][200][128] packed hi|lo
    const float* __restrict__ Bm,        // [3][200]
    const int* __restrict__ seq,         // [B]
    const float* __restrict__ acc0, const float* __restrict__ acc1,
    float* __restrict__ part,            // [2048][PSTR]
    float* __restrict__ out, int iter) {
    __shared__ float sW[SEQ * 4];          // [l][k], k<3 used (3.2 KB)
    __shared__ float pB[4][3][HALF];       // per-wave Pass-B partials (3 KB)
    __shared__ float sH[3][HALF];          // squashed high (0.75 KB)

    const int t = threadIdx.x;
    const int lane = t & 63, w = t >> 6;
    const int b = blockIdx.x >> 1, half = blockIdx.x & 1;
    const unsigned* lp = lowp + (size_t)b * (SEQ * DIN) + half * HALF;
    const int n = seq[b];

    // (1) softmax over logits (waves 0..2, one k each)
    if (w < 3) {
        const int k = w;
        float vv[4], m = -INFINITY;
#pragma unroll
        for (int i = 0; i < 4; ++i) {
            int l = lane + 64 * i;
            bool inb = (l < SEQ);
            float v = inb ? Bm[k * SEQ + l] : 0.f;
            if (iter >= 1 && inb) v += acc0[k * SEQ + l];
            if (iter >= 2 && inb) v += acc1[k * SEQ + l];
            vv[i] = (l < n) ? v : -INFINITY;   // l<n implies l<SEQ
            if (l < n) m = fmaxf(m, v);
        }
        for (int off = 32; off; off >>= 1) m = fmaxf(m, __shfl_xor(m, off, 64));
        float s = 0.f, pv[4];
#pragma unroll
        for (int i = 0; i < 4; ++i) {
            pv[i] = (vv[i] == -INFINITY) ? 0.f : expf(vv[i] - m);
            s += pv[i];
        }
        for (int off = 32; off; off >>= 1) s += __shfl_xor(s, off, 64);
        float rs = 1.f / s;
#pragma unroll
        for (int i = 0; i < 4; ++i) {
            int l = lane + 64 * i;
            if (l < SEQ) sW[l * 4 + k] = pv[i] * rs;
        }
    }
    __syncthreads();

    // (2) Pass B: H = W @ low_new. wave w sums l in [50w, 50w+50); lane = e.
    //     Global reads, coalesced 256B/wave-inst, L2/LLC-resident.
    {
        const int e = lane;
        const unsigned* col = lp + e;
        float h0 = 0.f, h1 = 0.f, h2 = 0.f;
#pragma unroll 10
        for (int i = 0; i < 50; ++i) {
            int l = w * 50 + i;
            float4 wv = *(const float4*)&sW[l * 4];   // wave-uniform broadcast
            float f = unpk(col[(size_t)l * DIN]);
            h0 = fmaf(wv.x, f, h0);
            h1 = fmaf(wv.y, f, h1);
            h2 = fmaf(wv.z, f, h2);
        }
        pB[w][0][e] = h0; pB[w][1][e] = h1; pB[w][2][e] = h2;
    }
    __syncthreads();

    // (3) cross-wave reduce + squash (single wave)
    if (t < HALF) {
        float g0 = pB[0][0][t] + pB[1][0][t] + pB[2][0][t] + pB[3][0][t];
        float g1 = pB[0][1][t] + pB[1][1][t] + pB[2][1][t] + pB[3][1][t];
        float g2 = pB[0][2][t] + pB[1][2][t] + pB[2][2][t] + pB[3][2][t];
        float sq = g0 * g0 + g1 * g1 + g2 * g2;
        float scale = sq / (1.f + sq) / sqrtf(sq + 1e-9f);
        g0 *= scale; g1 *= scale; g2 *= scale;
        if (iter == 2) {
            size_t o = (size_t)b * 3 * DOUT + half * HALF + t;
            out[o] = g0; out[o + DOUT] = g1; out[o + 2 * DOUT] = g2;
        } else {
            sH[0][t] = g0; sH[1][t] = g1; sH[2][t] = g2;
        }
    }
    if (iter == 2) return;   // uniform exit
    __syncthreads();

    // (4) Pass C: B_delta partials; thread = l, reads its own row (16B/lane
    //     gathers, L2-resident). sH reads are wave-uniform broadcasts.
    if (t < SEQ) {
        const int l = t;
        const unsigned* row = lp + (size_t)l * DIN;
        float d0 = 0.f, d1 = 0.f, d2 = 0.f;
#pragma unroll
        for (int j = 0; j < 16; ++j) {
            uint4 u = *(const uint4*)&row[4 * j];
            float4 x0 = *(const float4*)&sH[0][4 * j];
            float4 x1 = *(const float4*)&sH[1][4 * j];
            float4 x2 = *(const float4*)&sH[2][4 * j];
            float f0 = unpk(u.x), f1 = unpk(u.y), f2 = unpk(u.z), f3 = unpk(u.w);
            d0 += x0.x * f0 + x0.y * f1 + x0.z * f2 + x0.w * f3;
            d1 += x1.x * f0 + x1.y * f1 + x1.z * f2 + x1.w * f3;
            d2 += x2.x * f0 + x2.y * f1 + x2.z * f2 + x2.w * f3;
        }
        float* pp = part + (size_t)blockIdx.x * PSTR;
        pp[l] = d0;
        pp[SEQ + l] = d1;
        pp[2 * SEQ + l] = d2;
    }
}

// ---- K3: column-sum part[2048][PSTR] -> accN[600]; 150 blocks x 4 cols ----
__global__ __launch_bounds__(256) void k_reduce(const float* __restrict__ part,
                                                float* __restrict__ accN) {
    __shared__ float sP[4][4];
    const int t = threadIdx.x, lane = t & 63, w = t >> 6;
    const int c4 = blockIdx.x * 4;
    float sx = 0.f, sy = 0.f, sz = 0.f, sw = 0.f;
#pragma unroll
    for (int i = 0; i < 8; ++i) {
        float4 v = *(const float4*)&part[(size_t)(t + 256 * i) * PSTR + c4];
        sx += v.x; sy += v.y; sz += v.z; sw += v.w;
    }
#pragma unroll
    for (int off = 1; off < 64; off <<= 1) {
        sx += __shfl_xor(sx, off, 64);
        sy += __shfl_xor(sy, off, 64);
        sz += __shfl_xor(sz, off, 64);
        sw += __shfl_xor(sw, off, 64);
    }
    if (lane == 0) { sP[w][0] = sx; sP[w][1] = sy; sP[w][2] = sz; sP[w][3] = sw; }
    __syncthreads();
    if (t < 4)
        accN[c4 + t] = sP[0][t] + sP[1][t] + sP[2][t] + sP[3][t];
}

extern "C" void kernel_launch(void* const* d_in, const int* in_sizes, int n_in,
                              void* d_out, int out_size, void* d_ws, size_t ws_size,
                              hipStream_t stream) {
    const float* low_capsule = (const float*)d_in[0];   // [1024][200][128]
    const float* B_matrix    = (const float*)d_in[1];   // [1][3][200]
    const float* S_matrix    = (const float*)d_in[2];   // [128][128]
    const int*   seq_len     = (const int*)d_in[3];     // [1024]
    float* out = (float*)d_out;                         // [1024][3][128]

    unsigned* lowp = (unsigned*)d_ws;                              // 26,214,400 u32
    short* Sp      = (short*)(lowp + (size_t)BATCH * SEQ * DOUT);  // 32768 shorts
    float* acc0    = (float*)(Sp + 32768);                         // 600
    float* acc1    = acc0 + 640;                                   // 600
    float* part    = acc1 + 640;                                   // 2048 * PSTR

    k_presplit<<<64, 256, 0, stream>>>(S_matrix, Sp);
    k_gemm<<<(BATCH * SEQ) / 128, 256, 0, stream>>>(low_capsule, Sp, lowp);

    k_iter<<<2 * BATCH, 256, 0, stream>>>(lowp, B_matrix, seq_len, acc0, acc1, part, out, 0);
    k_reduce<<<150, 256, 0, stream>>>(part, acc0);
    k_iter<<<2 * BATCH, 256, 0, stream>>>(lowp, B_matrix, seq_len, acc0, acc1, part, out, 1);
    k_reduce<<<150, 256, 0, stream>>>(part, acc1);
    k_iter<<<2 * BATCH, 256, 0, stream>>>(lowp, B_matrix, seq_len, acc0, acc1, part, out, 2);
}

// Round 3
// 280.370 us; speedup vs baseline: 1.1072x; 1.1072x over previous
//
#include <hip/hip_runtime.h>
#include <math.h>

#define BATCH 1024
#define SEQ   200
#define DIN   128
#define DOUT  128
#define PSTR  608    // partial-delta row stride (floats): 600 data + 8 pad

typedef __attribute__((ext_vector_type(8))) short short8;
typedef __attribute__((ext_vector_type(4))) float f32x4;

// async global->LDS, 16B per lane; LDS dest = wave-uniform base + lane*16
__device__ __forceinline__ void async_copy16(const void* g, void* l) {
    __builtin_amdgcn_global_load_lds((const __attribute__((address_space(1))) void*)g,
                                     (__attribute__((address_space(3))) void*)l,
                                     16, 0, 0);
}

// fp32 -> packed (bf16_hi << 16) | bf16_lo ; hi = round-half-up, lo = RTZ residual
__device__ __forceinline__ unsigned pack_split(float f) {
    unsigned u = __float_as_uint(f);
    unsigned r = u + 0x8000u;
    unsigned hi = r >> 16;
    float hf = __uint_as_float(r & 0xffff0000u);
    unsigned lo = __float_as_uint(f - hf) >> 16;
    return (hi << 16) | lo;
}

__device__ __forceinline__ void split2(float f, short& h, short& l) {
    unsigned u = __float_as_uint(f);
    unsigned r = u + 0x8000u;
    h = (short)(r >> 16);
    float hf = __uint_as_float(r & 0xffff0000u);
    l = (short)(__float_as_uint(f - hf) >> 16);
}

// exact reconstruction of packed value
__device__ __forceinline__ float unpk(unsigned u) {
    return __uint_as_float(u & 0xffff0000u) + __uint_as_float(u << 16);
}

// ---- pre-split S into MFMA B-fragment order (hi at idx, lo at 16384+idx) ----
__global__ __launch_bounds__(256) void k_presplit(const float* __restrict__ S,
                                                  short* __restrict__ Sp) {
    int g = blockIdx.x * 256 + threadIdx.x;          // 0..16383
    int j = g & 7, lane = (g >> 3) & 63, kt = (g >> 9) & 3, nt = g >> 11;
    int k = kt * 32 + (lane >> 4) * 8 + j;
    int n = nt * 16 + (lane & 15);
    short h, l;
    split2(S[k * DOUT + n], h, l);
    Sp[g] = h;
    Sp[16384 + g] = l;
}

// ---- K1: low_new = A @ S ; PERSISTENT version.
//      512 blocks (2/CU, all co-resident). S staged into LDS ONCE per block.
//      Each wave independently processes 3-4 32-row tiles (6400 total) with
//      double-buffered A prefetch: LOADA(next) issued before COMPUTE(cur), so
//      HBM latency hides under the previous tile's split+MFMA+store.
//      (256,2): cap 256 unified regs; working set ~210 (bufA+bufB 64, frags 64,
//      acc 64 AGPR) -> NO spill (rounds 1-2 spilled at cap 128). ----
__global__ __launch_bounds__(256, 2) void k_gemm(const float* __restrict__ A,
                                                 const short* __restrict__ Sp,
                                                 unsigned* __restrict__ outp) {
    __shared__ short sSp[32768];   // 64 KB: hi [0..16383], lo [16384..]
    const int t = threadIdx.x;
    const int w = t >> 6, lane = t & 63;
    const int q = lane >> 4, c = lane & 15;

    // stage S once per block: 64 x 1KB async chunks, 16 per wave
#pragma unroll
    for (int i = 0; i < 16; ++i) {
        const int g = w * 16 + i;
        async_copy16(Sp + g * 512 + lane * 8, &sSp[g * 512]);
    }

    float4 bufA[4][2][2], bufB[4][2][2];

    auto LOADA = [&](float4 (&buf)[4][2][2], long rowb) {
#pragma unroll
        for (int kt = 0; kt < 4; ++kt)
#pragma unroll
            for (int mt = 0; mt < 2; ++mt) {
                const float* ap = A + (rowb + mt * 16 + c) * DIN + kt * 32 + q * 8;
                buf[kt][mt][0] = *(const float4*)ap;
                buf[kt][mt][1] = *(const float4*)(ap + 4);
            }
    };

    auto COMPUTE = [&](float4 (&buf)[4][2][2], long rowb) {
        short8 ah[4][2], al[4][2];
#pragma unroll
        for (int kt = 0; kt < 4; ++kt)
#pragma unroll
            for (int mt = 0; mt < 2; ++mt) {
                float av[8];
                *(float4*)&av[0] = buf[kt][mt][0];
                *(float4*)&av[4] = buf[kt][mt][1];
#pragma unroll
                for (int j = 0; j < 8; ++j) {
                    short h, l;
                    split2(av[j], h, l);
                    ah[kt][mt][j] = h; al[kt][mt][j] = l;
                }
            }
        f32x4 acc[2][8];
        const f32x4 zz = {0.f, 0.f, 0.f, 0.f};
#pragma unroll
        for (int mt = 0; mt < 2; ++mt)
#pragma unroll
            for (int nt = 0; nt < 8; ++nt) acc[mt][nt] = zz;
#pragma unroll
        for (int kt = 0; kt < 4; ++kt)
#pragma unroll
            for (int nt = 0; nt < 8; ++nt) {
                const int fo = ((nt * 4 + kt) * 64 + lane) * 8;
                short8 sh = *(const short8*)&sSp[fo];
                short8 sl = *(const short8*)&sSp[16384 + fo];
#pragma unroll
                for (int mt = 0; mt < 2; ++mt) {
                    acc[mt][nt] = __builtin_amdgcn_mfma_f32_16x16x32_bf16(ah[kt][mt], sh, acc[mt][nt], 0, 0, 0);
                    acc[mt][nt] = __builtin_amdgcn_mfma_f32_16x16x32_bf16(al[kt][mt], sh, acc[mt][nt], 0, 0, 0);
                    acc[mt][nt] = __builtin_amdgcn_mfma_f32_16x16x32_bf16(ah[kt][mt], sl, acc[mt][nt], 0, 0, 0);
                }
            }
        // C/D: col = lane&15, row = (lane>>4)*4 + r
#pragma unroll
        for (int mt = 0; mt < 2; ++mt)
#pragma unroll
            for (int nt = 0; nt < 8; ++nt) {
                long r0 = rowb + mt * 16 + q * 4;
#pragma unroll
                for (int r = 0; r < 4; ++r)
                    outp[(r0 + r) * DOUT + nt * 16 + c] = pack_split(acc[mt][nt][r]);
            }
    };

    // wave-tile schedule: 6400 tiles of 32 rows; 2048 waves; stride 2048.
    // base < 256 gets a 4th tile. All branches wave-uniform.
    const int base = blockIdx.x * 4 + w;            // 0..2047
    const long r0 = (long)base * 32;
    const long r1 = r0 + (long)2048 * 32;
    const long r2 = r1 + (long)2048 * 32;
    const long r3 = r2 + (long)2048 * 32;
    const bool h3 = (base < 256);

    // first two tiles' loads overlap the S-stage + barrier
    LOADA(bufA, r0);
    LOADA(bufB, r1);
    __syncthreads();   // drains async S stage (A loads also retired by then)

    COMPUTE(bufA, r0);
    LOADA(bufA, r2);
    COMPUTE(bufB, r1);
    if (h3) {
        LOADA(bufB, r3);
        COMPUTE(bufA, r2);
        COMPUTE(bufB, r3);
    } else {
        COMPUTE(bufA, r2);
    }
}

// ---- K2: one routing iteration; ONE block per batch element (halves merged:
//      softmax/seq-load once per b, Pass-B streams full 512B rows, Pass-C
//      gathers halve instruction count). LDS ~11 KB; (256,4) cap 128 regs. ----
__global__ __launch_bounds__(256, 4) void k_iter(
    const unsigned* __restrict__ lowp,   // [B][200][128] packed hi|lo
    const float* __restrict__ Bm,        // [3][200]
    const int* __restrict__ seq,         // [B]
    const float* __restrict__ acc0, const float* __restrict__ acc1,
    float* __restrict__ part,            // [1024][PSTR]
    float* __restrict__ out, int iter) {
    __shared__ float sW[SEQ * 4];          // [l][k], k<3 used (3.2 KB)
    __shared__ float pB[4][3][DIN];        // per-wave Pass-B partials (6 KB)
    __shared__ float sH[3][DIN];           // squashed high (1.5 KB)

    const int t = threadIdx.x;
    const int lane = t & 63, w = t >> 6;
    const int b = blockIdx.x;
    const unsigned* lp = lowp + (size_t)b * (SEQ * DIN);
    const int n = seq[b];

    // (1) softmax over logits (waves 0..2, one k each)
    if (w < 3) {
        const int k = w;
        float vv[4], m = -INFINITY;
#pragma unroll
        for (int i = 0; i < 4; ++i) {
            int l = lane + 64 * i;
            bool inb = (l < SEQ);
            float v = inb ? Bm[k * SEQ + l] : 0.f;
            if (iter >= 1 && inb) v += acc0[k * SEQ + l];
            if (iter >= 2 && inb) v += acc1[k * SEQ + l];
            vv[i] = (l < n) ? v : -INFINITY;   // l<n implies l<SEQ
            if (l < n) m = fmaxf(m, v);
        }
        for (int off = 32; off; off >>= 1) m = fmaxf(m, __shfl_xor(m, off, 64));
        float s = 0.f, pv[4];
#pragma unroll
        for (int i = 0; i < 4; ++i) {
            pv[i] = (vv[i] == -INFINITY) ? 0.f : expf(vv[i] - m);
            s += pv[i];
        }
        for (int off = 32; off; off >>= 1) s += __shfl_xor(s, off, 64);
        float rs = 1.f / s;
#pragma unroll
        for (int i = 0; i < 4; ++i) {
            int l = lane + 64 * i;
            if (l < SEQ) sW[l * 4 + k] = pv[i] * rs;
        }
    }
    __syncthreads();

    // (2) Pass B: H = W @ low_new. wave w sums l in [50w, 50w+50); both e-halves.
    //     Reads 512B-contiguous per row, L2/LLC-resident.
    {
        const unsigned* c0 = lp + lane;
        const unsigned* c1 = lp + 64 + lane;
        float h0a = 0.f, h1a = 0.f, h2a = 0.f;
        float h0b = 0.f, h1b = 0.f, h2b = 0.f;
#pragma unroll 10
        for (int i = 0; i < 50; ++i) {
            int l = w * 50 + i;
            float4 wv = *(const float4*)&sW[l * 4];   // wave-uniform broadcast
            float fa = unpk(c0[(size_t)l * DIN]);
            float fb = unpk(c1[(size_t)l * DIN]);
            h0a = fmaf(wv.x, fa, h0a); h0b = fmaf(wv.x, fb, h0b);
            h1a = fmaf(wv.y, fa, h1a); h1b = fmaf(wv.y, fb, h1b);
            h2a = fmaf(wv.z, fa, h2a); h2b = fmaf(wv.z, fb, h2b);
        }
        pB[w][0][lane] = h0a; pB[w][0][64 + lane] = h0b;
        pB[w][1][lane] = h1a; pB[w][1][64 + lane] = h1b;
        pB[w][2][lane] = h2a; pB[w][2][64 + lane] = h2b;
    }
    __syncthreads();

    // (3) cross-wave reduce + squash (2 waves; norm is over k per (b,e))
    if (t < DIN) {
        float g0 = pB[0][0][t] + pB[1][0][t] + pB[2][0][t] + pB[3][0][t];
        float g1 = pB[0][1][t] + pB[1][1][t] + pB[2][1][t] + pB[3][1][t];
        float g2 = pB[0][2][t] + pB[1][2][t] + pB[2][2][t] + pB[3][2][t];
        float sq = g0 * g0 + g1 * g1 + g2 * g2;
        float scale = sq / (1.f + sq) / sqrtf(sq + 1e-9f);
        g0 *= scale; g1 *= scale; g2 *= scale;
        if (iter == 2) {
            size_t o = (size_t)b * 3 * DOUT + t;
            out[o] = g0; out[o + DOUT] = g1; out[o + 2 * DOUT] = g2;
        } else {
            sH[0][t] = g0; sH[1][t] = g1; sH[2][t] = g2;
        }
    }
    if (iter == 2) return;   // uniform exit
    __syncthreads();

    // (4) Pass C: B_delta partials; thread = l reads its full 512B row
    //     (4 cache lines/thread), sH reads wave-uniform broadcasts.
    if (t < SEQ) {
        const unsigned* row = lp + (size_t)t * DIN;
        float d0 = 0.f, d1 = 0.f, d2 = 0.f;
#pragma unroll
        for (int j = 0; j < 32; ++j) {
            uint4 u = *(const uint4*)&row[4 * j];
            float4 x0 = *(const float4*)&sH[0][4 * j];
            float4 x1 = *(const float4*)&sH[1][4 * j];
            float4 x2 = *(const float4*)&sH[2][4 * j];
            float f0 = unpk(u.x), f1 = unpk(u.y), f2 = unpk(u.z), f3 = unpk(u.w);
            d0 += x0.x * f0 + x0.y * f1 + x0.z * f2 + x0.w * f3;
            d1 += x1.x * f0 + x1.y * f1 + x1.z * f2 + x1.w * f3;
            d2 += x2.x * f0 + x2.y * f1 + x2.z * f2 + x2.w * f3;
        }
        float* pp = part + (size_t)b * PSTR;
        pp[t] = d0;
        pp[SEQ + t] = d1;
        pp[2 * SEQ + t] = d2;
    }
}

// ---- K3: column-sum part[1024][PSTR] -> accN[600]; 150 blocks x 4 cols ----
__global__ __launch_bounds__(256) void k_reduce(const float* __restrict__ part,
                                                float* __restrict__ accN) {
    __shared__ float sP[4][4];
    const int t = threadIdx.x, lane = t & 63, w = t >> 6;
    const int c4 = blockIdx.x * 4;
    float sx = 0.f, sy = 0.f, sz = 0.f, sw = 0.f;
#pragma unroll
    for (int i = 0; i < 4; ++i) {
        float4 v = *(const float4*)&part[(size_t)(t + 256 * i) * PSTR + c4];
        sx += v.x; sy += v.y; sz += v.z; sw += v.w;
    }
#pragma unroll
    for (int off = 1; off < 64; off <<= 1) {
        sx += __shfl_xor(sx, off, 64);
        sy += __shfl_xor(sy, off, 64);
        sz += __shfl_xor(sz, off, 64);
        sw += __shfl_xor(sw, off, 64);
    }
    if (lane == 0) { sP[w][0] = sx; sP[w][1] = sy; sP[w][2] = sz; sP[w][3] = sw; }
    __syncthreads();
    if (t < 4)
        accN[c4 + t] = sP[0][t] + sP[1][t] + sP[2][t] + sP[3][t];
}

extern "C" void kernel_launch(void* const* d_in, const int* in_sizes, int n_in,
                              void* d_out, int out_size, void* d_ws, size_t ws_size,
                              hipStream_t stream) {
    const float* low_capsule = (const float*)d_in[0];   // [1024][200][128]
    const float* B_matrix    = (const float*)d_in[1];   // [1][3][200]
    const float* S_matrix    = (const float*)d_in[2];   // [128][128]
    const int*   seq_len     = (const int*)d_in[3];     // [1024]
    float* out = (float*)d_out;                         // [1024][3][128]

    unsigned* lowp = (unsigned*)d_ws;                              // 26,214,400 u32
    short* Sp      = (short*)(lowp + (size_t)BATCH * SEQ * DOUT);  // 32768 shorts
    float* acc0    = (float*)(Sp + 32768);                         // 600
    float* acc1    = acc0 + 640;                                   // 600
    float* part    = acc1 + 640;                                   // 1024 * PSTR

    k_presplit<<<64, 256, 0, stream>>>(S_matrix, Sp);
    k_gemm<<<512, 256, 0, stream>>>(low_capsule, Sp, lowp);

    k_iter<<<BATCH, 256, 0, stream>>>(lowp, B_matrix, seq_len, acc0, acc1, part, out, 0);
    k_reduce<<<150, 256, 0, stream>>>(part, acc0);
    k_iter<<<BATCH, 256, 0, stream>>>(lowp, B_matrix, seq_len, acc0, acc1, part, out, 1);
    k_reduce<<<150, 256, 0, stream>>>(part, acc1);
    k_iter<<<BATCH, 256, 0, stream>>>(lowp, B_matrix, seq_len, acc0, acc1, part, out, 2);
}

// Round 4
// 246.952 us; speedup vs baseline: 1.2570x; 1.1353x over previous
//
#include <hip/hip_runtime.h>
#include <math.h>

#define BATCH 1024
#define SEQ   200
#define DIN   128
#define DOUT  128
#define PSTR  608    // partial-delta row stride (floats): 600 data + 8 pad

// ---- K0: transpose S (64 KB, one-time) so both S and S^T are coalesced ----
__global__ __launch_bounds__(256) void k_transpose(const float* __restrict__ S,
                                                   float* __restrict__ ST) {
    int idx = blockIdx.x * 256 + threadIdx.x;   // 0..16383
    int d = idx >> 7, e = idx & 127;
    ST[e * DIN + d] = S[d * DOUT + e];
}

// ---- K1: one routing iteration, low_new NEVER materialized.
//      Uses (W@A)@S == W@(A@S) and (high@S^T)@A^T == high@(A@S)^T.
//      Per block (one batch b): softmax -> WA[3,128] -> high=squash(WA@S)
//      -> hS=high@S^T -> B_delta partials = hS@A^T.
//      A read twice per block (coalesced, LLC-resident), S/ST from L2.
//      LDS ~14 KB -> 4 blocks/CU; whole 1024-block grid co-resident. ----
__global__ __launch_bounds__(256) void k_iter(
    const float* __restrict__ A,         // [B][200][128] fp32
    const float* __restrict__ S,         // [128][128]
    const float* __restrict__ ST,        // [128][128] transposed
    const float* __restrict__ Bm,        // [3][200]
    const int* __restrict__ seq,         // [B]
    const float* __restrict__ acc0, const float* __restrict__ acc1,
    float* __restrict__ part,            // [1024][PSTR]
    float* __restrict__ out, int iter) {
    __shared__ float sW[SEQ * 4];          // [l][k], k<3 used (3.2 KB)
    __shared__ float pB[4][3][DIN];        // partials, reused across phases (6 KB)
    __shared__ float sWA[3][DIN];          // W @ A   (1.5 KB)
    __shared__ float sH[3][DIN];           // squash(WA @ S) (1.5 KB)
    __shared__ float sHS[3][DIN];          // high @ S^T (1.5 KB)

    const int t = threadIdx.x;
    const int lane = t & 63, w = t >> 6;
    const int b = blockIdx.x;
    const float* Ab = A + (size_t)b * (SEQ * DIN);
    const int n = seq[b];

    // (1) softmax over logits (waves 0..2, one k each); sW=0 for l>=n
    if (w < 3) {
        const int k = w;
        float vv[4], m = -INFINITY;
#pragma unroll
        for (int i = 0; i < 4; ++i) {
            int l = lane + 64 * i;
            bool inb = (l < SEQ);
            float v = inb ? Bm[k * SEQ + l] : 0.f;
            if (iter >= 1 && inb) v += acc0[k * SEQ + l];
            if (iter >= 2 && inb) v += acc1[k * SEQ + l];
            vv[i] = (l < n) ? v : -INFINITY;   // l<n implies l<SEQ
            if (l < n) m = fmaxf(m, v);
        }
        for (int off = 32; off; off >>= 1) m = fmaxf(m, __shfl_xor(m, off, 64));
        float s = 0.f, pv[4];
#pragma unroll
        for (int i = 0; i < 4; ++i) {
            pv[i] = (vv[i] == -INFINITY) ? 0.f : expf(vv[i] - m);
            s += pv[i];
        }
        for (int off = 32; off; off >>= 1) s += __shfl_xor(s, off, 64);
        float rs = 1.f / s;
#pragma unroll
        for (int i = 0; i < 4; ++i) {
            int l = lane + 64 * i;
            if (l < SEQ) sW[l * 4 + k] = pv[i] * rs;
        }
    }
    __syncthreads();

    // (2) WA partials: wave w sums l in [50w,50w+50); lane covers d=2*lane,2*lane+1.
    //     float2 loads: 512B contiguous per row per wave (coalesced, LLC).
    {
        const float2* a2 = (const float2*)Ab;    // row stride 64 float2
        float h00 = 0.f, h01 = 0.f, h10 = 0.f, h11 = 0.f, h20 = 0.f, h21 = 0.f;
#pragma unroll 10
        for (int i = 0; i < 50; ++i) {
            int l = w * 50 + i;
            float4 wv = *(const float4*)&sW[l * 4];   // wave-uniform broadcast
            float2 v = a2[(size_t)l * 64 + lane];
            h00 = fmaf(wv.x, v.x, h00); h01 = fmaf(wv.x, v.y, h01);
            h10 = fmaf(wv.y, v.x, h10); h11 = fmaf(wv.y, v.y, h11);
            h20 = fmaf(wv.z, v.x, h20); h21 = fmaf(wv.z, v.y, h21);
        }
        pB[w][0][2 * lane] = h00; pB[w][0][2 * lane + 1] = h01;
        pB[w][1][2 * lane] = h10; pB[w][1][2 * lane + 1] = h11;
        pB[w][2][2 * lane] = h20; pB[w][2][2 * lane + 1] = h21;
    }
    __syncthreads();

    // (3a) reduce WA across waves
    if (t < DIN) {
#pragma unroll
        for (int k = 0; k < 3; ++k)
            sWA[k][t] = pB[0][k][t] + pB[1][k][t] + pB[2][k][t] + pB[3][k][t];
    }
    __syncthreads();

    // (3b) high_raw = WA @ S ; all 256 threads: e = t&127, half hh of d-range.
    //      S[d][e] loads coalesced across e.
    {
        const int e = t & 127, hh = t >> 7;
        const float* Scol = S + e;
        float g0 = 0.f, g1 = 0.f, g2 = 0.f;
#pragma unroll 8
        for (int i = 0; i < 64; ++i) {
            int d = hh * 64 + i;
            float sv = Scol[d * DOUT];
            g0 = fmaf(sWA[0][d], sv, g0);
            g1 = fmaf(sWA[1][d], sv, g1);
            g2 = fmaf(sWA[2][d], sv, g2);
        }
        pB[hh][0][e] = g0; pB[hh][1][e] = g1; pB[hh][2][e] = g2;
    }
    __syncthreads();

    // (3c) combine halves + squash (norm over k per (b,e)); write out on last iter
    if (t < DIN) {
        float g0 = pB[0][0][t] + pB[1][0][t];
        float g1 = pB[0][1][t] + pB[1][1][t];
        float g2 = pB[0][2][t] + pB[1][2][t];
        float sq = g0 * g0 + g1 * g1 + g2 * g2;
        float scale = sq / (1.f + sq) / sqrtf(sq + 1e-9f);
        g0 *= scale; g1 *= scale; g2 *= scale;
        if (iter == 2) {
            size_t o = (size_t)b * 3 * DOUT + t;
            out[o] = g0; out[o + DOUT] = g1; out[o + 2 * DOUT] = g2;
        } else {
            sH[0][t] = g0; sH[1][t] = g1; sH[2][t] = g2;
        }
    }
    if (iter == 2) return;   // uniform exit
    __syncthreads();

    // (4a) hS = high @ S^T ; d = t&127, half hh of e-range.
    //      ST[e][d] loads coalesced across d.
    {
        const int d = t & 127, hh = t >> 7;
        const float* STcol = ST + d;
        float s0 = 0.f, s1 = 0.f, s2 = 0.f;
#pragma unroll 8
        for (int i = 0; i < 64; ++i) {
            int e = hh * 64 + i;
            float sv = STcol[e * DIN];
            s0 = fmaf(sH[0][e], sv, s0);
            s1 = fmaf(sH[1][e], sv, s1);
            s2 = fmaf(sH[2][e], sv, s2);
        }
        pB[hh][0][d] = s0; pB[hh][1][d] = s1; pB[hh][2][d] = s2;
    }
    __syncthreads();

    if (t < DIN) {
#pragma unroll
        for (int k = 0; k < 3; ++k)
            sHS[k][t] = pB[0][k][t] + pB[1][k][t];
    }
    __syncthreads();

    // (5) B_delta partials: thread = l reads its full 512B A-row (coalesced
    //     float4 within thread, LLC-resident); sHS reads wave-uniform.
    if (t < SEQ) {
        const float* row = Ab + (size_t)t * DIN;
        float d0 = 0.f, d1 = 0.f, d2 = 0.f;
#pragma unroll
        for (int j = 0; j < 32; ++j) {
            float4 u = *(const float4*)&row[4 * j];
            float4 x0 = *(const float4*)&sHS[0][4 * j];
            float4 x1 = *(const float4*)&sHS[1][4 * j];
            float4 x2 = *(const float4*)&sHS[2][4 * j];
            d0 += x0.x * u.x + x0.y * u.y + x0.z * u.z + x0.w * u.w;
            d1 += x1.x * u.x + x1.y * u.y + x1.z * u.z + x1.w * u.w;
            d2 += x2.x * u.x + x2.y * u.y + x2.z * u.z + x2.w * u.w;
        }
        float* pp = part + (size_t)b * PSTR;
        pp[t] = d0;
        pp[SEQ + t] = d1;
        pp[2 * SEQ + t] = d2;
    }
}

// ---- K3: column-sum part[1024][PSTR] -> accN[600]; 150 blocks x 4 cols ----
__global__ __launch_bounds__(256) void k_reduce(const float* __restrict__ part,
                                                float* __restrict__ accN) {
    __shared__ float sP[4][4];
    const int t = threadIdx.x, lane = t & 63, w = t >> 6;
    const int c4 = blockIdx.x * 4;
    float sx = 0.f, sy = 0.f, sz = 0.f, sw = 0.f;
#pragma unroll
    for (int i = 0; i < 4; ++i) {
        float4 v = *(const float4*)&part[(size_t)(t + 256 * i) * PSTR + c4];
        sx += v.x; sy += v.y; sz += v.z; sw += v.w;
    }
#pragma unroll
    for (int off = 1; off < 64; off <<= 1) {
        sx += __shfl_xor(sx, off, 64);
        sy += __shfl_xor(sy, off, 64);
        sz += __shfl_xor(sz, off, 64);
        sw += __shfl_xor(sw, off, 64);
    }
    if (lane == 0) { sP[w][0] = sx; sP[w][1] = sy; sP[w][2] = sz; sP[w][3] = sw; }
    __syncthreads();
    if (t < 4)
        accN[c4 + t] = sP[0][t] + sP[1][t] + sP[2][t] + sP[3][t];
}

extern "C" void kernel_launch(void* const* d_in, const int* in_sizes, int n_in,
                              void* d_out, int out_size, void* d_ws, size_t ws_size,
                              hipStream_t stream) {
    const float* low_capsule = (const float*)d_in[0];   // [1024][200][128]
    const float* B_matrix    = (const float*)d_in[1];   // [1][3][200]
    const float* S_matrix    = (const float*)d_in[2];   // [128][128]
    const int*   seq_len     = (const int*)d_in[3];     // [1024]
    float* out = (float*)d_out;                         // [1024][3][128]

    float* ST   = (float*)d_ws;          // 16384
    float* acc0 = ST + 16384;            // 600 (+pad)
    float* acc1 = acc0 + 640;            // 600 (+pad)
    float* part = acc1 + 640;            // 1024 * PSTR

    k_transpose<<<64, 256, 0, stream>>>(S_matrix, ST);

    k_iter<<<BATCH, 256, 0, stream>>>(low_capsule, S_matrix, ST, B_matrix,
                                      seq_len, acc0, acc1, part, out, 0);
    k_reduce<<<150, 256, 0, stream>>>(part, acc0);
    k_iter<<<BATCH, 256, 0, stream>>>(low_capsule, S_matrix, ST, B_matrix,
                                      seq_len, acc0, acc1, part, out, 1);
    k_reduce<<<150, 256, 0, stream>>>(part, acc1);
    k_iter<<<BATCH, 256, 0, stream>>>(low_capsule, S_matrix, ST, B_matrix,
                                      seq_len, acc0, acc1, part, out, 2);
}